// Round 17
// baseline (200.988 us; speedup 1.0000x reference)
//
#include <hip/hip_runtime.h>
#include <hip/hip_fp16.h>

#define DIM 256
#define MARGIN 2.25e-4f

typedef __bf16 bf8v __attribute__((ext_vector_type(8)));
typedef float f4v __attribute__((ext_vector_type(4)));

__device__ inline unsigned short f2bf(float x) {
    unsigned u = __float_as_uint(x);
    u += 0x7fffu + ((u >> 16) & 1u);   // RNE
    return (unsigned short)(u >> 16);
}

// ---------------- fused prep (R22 layout: 2048 transpose + 1024 emb + 1 loss) ----------------
// eb is TILED (ebT): group g (16 codes) x K-step kk: 1024B tile [q(4)][m(16)][8 dims].
__global__ __launch_bounds__(256) void k_prep(const float* __restrict__ z,
                                              const float* __restrict__ emb,
                                              float* __restrict__ zf,
                                              unsigned short* __restrict__ zb,
                                              unsigned short* __restrict__ eb,
                                              float* __restrict__ enorm,
                                              float* __restrict__ out_loss) {
    const int bx = blockIdx.x;
    if (bx < 2048) {
        __shared__ float tt[32][33];
        const int hw0 = (bx & 31) * 32;
        const int d0  = ((bx >> 5) & 7) * 32;
        const int b   = bx >> 8;
        const int tx = threadIdx.x & 31, ty = threadIdx.x >> 5;
#pragma unroll
        for (int i = 0; i < 4; i++) {
            const int d = d0 + ty + 8 * i;
            tt[ty + 8 * i][tx] = z[(b * 256 + d) * 1024 + hw0 + tx];
        }
        __syncthreads();
#pragma unroll
        for (int i = 0; i < 4; i++) {
            const int hw = hw0 + ty + 8 * i;
            const float v = tt[tx][ty + 8 * i];
            const size_t o = (size_t)(b * 1024 + hw) * DIM + d0 + tx;
            zf[o] = v;
            zb[o] = f2bf(v);
        }
    } else if (bx < 3072) {
        const int s2 = bx - 2048;
        const int wave = threadIdx.x >> 6, lane = threadIdx.x & 63;
#pragma unroll
        for (int j = 0; j < 4; j++) {
            const int row = s2 * 16 + j * 4 + wave;
            const float4 v = *(const float4*)(emb + (size_t)row * DIM + lane * 4);
            ushort4 o;
            o.x = f2bf(v.x); o.y = f2bf(v.y); o.z = f2bf(v.z); o.w = f2bf(v.w);
            const int g = row >> 4, m = row & 15;
            const int kk = lane >> 3, qq = (lane >> 1) & 3, e = (lane & 1) * 4;
            *(ushort4*)(eb + (size_t)(g * 8 + kk) * 512 + qq * 128 + m * 8 + e) = o;
            float ss = v.x * v.x + v.y * v.y + v.z * v.z + v.w * v.w;
#pragma unroll
            for (int m2 = 1; m2 < 64; m2 <<= 1) ss += __shfl_xor(ss, m2, 64);
            if (lane == 0) enorm[row] = ss;
        }
    } else {
        if (threadIdx.x == 0) out_loss[0] = 0.f;
    }
}

// ---------------- bf16 MFMA scoring (R20 EXACT -- measured best: 70.6us, MfmaUtil 43%) -------
// Depth-2 B pipeline + Af double-buffer at (256,3): 84 arch VGPR + 64 AGPR = 148/170.
#define GLOADB(dst, voff, base) \
    asm volatile("global_load_dwordx4 %0, %1, %2" : "=&v"(dst) : "v"(voff), "s"(base))
#define SO(KK) ((unsigned)((((KK) >> 3) * 131072) + (((KK) & 7) * 1024)))

#define ISSUE(sl, KK) \
    GLOADB(Bp##sl##_0, voffb0 + SO(KK), eb); \
    GLOADB(Bp##sl##_1, voffb1 + SO(KK), eb); \
    GLOADB(Bp##sl##_2, voffb2 + SO(KK), eb); \
    GLOADB(Bp##sl##_3, voffb3 + SO(KK), eb);

#define MFMA4(rt, AF, sl) \
    acc[rt][0] = __builtin_amdgcn_mfma_f32_16x16x32_bf16(AF, Bp##sl##_0, acc[rt][0], 0, 0, 0); \
    acc[rt][1] = __builtin_amdgcn_mfma_f32_16x16x32_bf16(AF, Bp##sl##_1, acc[rt][1], 0, 0, 0); \
    acc[rt][2] = __builtin_amdgcn_mfma_f32_16x16x32_bf16(AF, Bp##sl##_2, acc[rt][2], 0, 0, 0); \
    acc[rt][3] = __builtin_amdgcn_mfma_f32_16x16x32_bf16(AF, Bp##sl##_3, acc[rt][3], 0, 0, 0);

#define PF(dp, kk) { \
    const int slot_ = (((kk) * 4 + q) ^ m15) * 8; \
    Af##dp##_0 = *(const bf8v*)&As[(m15)      * 256 + slot_]; \
    Af##dp##_1 = *(const bf8v*)&As[(16 + m15) * 256 + slot_]; \
    Af##dp##_2 = *(const bf8v*)&As[(32 + m15) * 256 + slot_]; \
    Af##dp##_3 = *(const bf8v*)&As[(48 + m15) * 256 + slot_]; }

#define CMP(P, sl) \
    __builtin_amdgcn_s_setprio(1); \
    MFMA4(0, Af##P##_0, sl) \
    MFMA4(1, Af##P##_1, sl) \
    MFMA4(2, Af##P##_2, sl) \
    MFMA4(3, Af##P##_3, sl) \
    __builtin_amdgcn_s_setprio(0);

#define WV(n) { asm volatile("s_waitcnt vmcnt(" #n ")" ::: "memory"); \
                __builtin_amdgcn_sched_barrier(0); }
#define SB __builtin_amdgcn_sched_barrier(0);

#define EPI(pp) { \
    const int by_ = nb * 4 + (pp); \
    const int gsl_ = wc * 4 + (m15 >> 2); \
    const float e0_ = en_lds[(pp) * 256 + wc * 64 +  0 + m15]; \
    const float e1_ = en_lds[(pp) * 256 + wc * 64 + 16 + m15]; \
    const float e2_ = en_lds[(pp) * 256 + wc * 64 + 32 + m15]; \
    const float e3_ = en_lds[(pp) * 256 + wc * 64 + 48 + m15]; \
    _Pragma("unroll") \
    for (int rt = 0; rt < 4; rt++) { \
        float sv[4]; \
        _Pragma("unroll") \
        for (int j = 0; j < 4; j++) { \
            float s_ = fmaf(-2.f, acc[rt][0][j], e0_); \
            s_ = fminf(s_, fmaf(-2.f, acc[rt][1][j], e1_)); \
            s_ = fminf(s_, fmaf(-2.f, acc[rt][2][j], e2_)); \
            s_ = fminf(s_, fmaf(-2.f, acc[rt][3][j], e3_)); \
            sv[j] = s_; \
        } \
        _Pragma("unroll") \
        for (int m = 1; m <= 2; m <<= 1) { \
            _Pragma("unroll") \
            for (int j = 0; j < 4; j++) sv[j] = fminf(sv[j], __shfl_xor(sv[j], m, 64)); \
        } \
        if ((m15 & 3) == 0) { \
            const int rl_ = rt * 16 + q * 4; \
            _Pragma("unroll") \
            for (int j = 0; j < 4; j++) \
                sm[(rl_ + j) * 16 + gsl_] = __half_as_ushort(__float2half_rn(sv[j])); \
        } \
    } \
    asm volatile("s_waitcnt lgkmcnt(0)" ::: "memory"); \
    __builtin_amdgcn_sched_barrier(0); \
    __builtin_amdgcn_s_barrier(); \
    __builtin_amdgcn_sched_barrier(0); \
    if (t < 128) { \
        const uint4 v_ = *(const uint4*)&sm[t * 8]; \
        *(uint4*)&pvalh[(size_t)(row0 + (t >> 1)) * 1024 + by_ * 16 + (t & 1) * 8] = v_; \
    } \
    __builtin_amdgcn_sched_barrier(0); \
    __builtin_amdgcn_s_barrier(); \
    __builtin_amdgcn_sched_barrier(0); \
    _Pragma("unroll") \
    for (int rt = 0; rt < 4; rt++) { \
        _Pragma("unroll") \
        for (int ct = 0; ct < 4; ct++) acc[rt][ct] = (f4v){0.f, 0.f, 0.f, 0.f}; \
    } }

__global__ __launch_bounds__(256, 3) void k_score(
        const unsigned short* __restrict__ zb, const unsigned short* __restrict__ eb,
        const float* __restrict__ enorm, unsigned short* __restrict__ pvalh) {
    __shared__ unsigned short As[64 * 256];   // 32 KB, swizzled: slot = chunk ^ (r&15)
    __shared__ unsigned short sm[64 * 16];    // 2 KB
    __shared__ float en_lds[1024];            // 4 KB
    const int bid = blockIdx.x;
    const int rx = (bid >> 3) & 127;
    const int nb = ((bid >> 10) << 3) + (bid & 7);
    const int row0 = rx * 64;
    const int t = threadIdx.x;
    const int lane = t & 63, wc = t >> 6;
    const int q = lane >> 4, m15 = lane & 15;

#pragma unroll
    for (int j = 0; j < 8; j++) {
        const int id = j * 256 + t;
        const int r = id >> 5, sl = id & 31;
        const int c = sl ^ (r & 15);
        __builtin_amdgcn_global_load_lds(
            (const __attribute__((address_space(1))) void*)(zb + (size_t)(row0 + r) * DIM + c * 8),
            (__attribute__((address_space(3))) void*)((char*)As + id * 16), 16, 0, 0);
    }
#pragma unroll
    for (int j = 0; j < 4; j++) {
        __builtin_amdgcn_global_load_lds(
            (const __attribute__((address_space(1))) void*)(enorm + nb * 1024 + j * 256 + t),
            (__attribute__((address_space(3))) void*)((char*)en_lds + (j * 256 + t) * 4), 4, 0, 0);
    }
    __syncthreads();

    f4v acc[4][4];
#pragma unroll
    for (int rt = 0; rt < 4; rt++)
#pragma unroll
        for (int ct = 0; ct < 4; ct++) acc[rt][ct] = (f4v){0.f, 0.f, 0.f, 0.f};

    const unsigned voffb0 = (unsigned)((nb * 64 + wc * 4 + 0) * 8192 + lane * 16);
    const unsigned voffb1 = (unsigned)((nb * 64 + wc * 4 + 1) * 8192 + lane * 16);
    const unsigned voffb2 = (unsigned)((nb * 64 + wc * 4 + 2) * 8192 + lane * 16);
    const unsigned voffb3 = (unsigned)((nb * 64 + wc * 4 + 3) * 8192 + lane * 16);

    bf8v Bp0_0, Bp0_1, Bp0_2, Bp0_3;
    bf8v Bp1_0, Bp1_1, Bp1_2, Bp1_3;
    bf8v Af0_0, Af0_1, Af0_2, Af0_3;
    bf8v Af1_0, Af1_1, Af1_2, Af1_3;

    ISSUE(0, 0) ISSUE(1, 1)
    PF(0, 0)

    WV(4) PF(1, 1) SB CMP(0, 0) ISSUE(0, 2)
    WV(4) PF(0, 2) SB CMP(1, 1) ISSUE(1, 3)
    WV(4) PF(1, 3) SB CMP(0, 0) ISSUE(0, 4)
    WV(4) PF(0, 4) SB CMP(1, 1) ISSUE(1, 5)
    WV(4) PF(1, 5) SB CMP(0, 0) ISSUE(0, 6)
    WV(4) PF(0, 6) SB CMP(1, 1) ISSUE(1, 7)
    WV(4) PF(1, 7) SB CMP(0, 0) ISSUE(0, 8)
    WV(4) PF(0, 0) SB CMP(1, 1) ISSUE(1, 9)
    EPI(0)
    WV(4) PF(1, 1) SB CMP(0, 0) ISSUE(0, 10)
    WV(4) PF(0, 2) SB CMP(1, 1) ISSUE(1, 11)
    WV(4) PF(1, 3) SB CMP(0, 0) ISSUE(0, 12)
    WV(4) PF(0, 4) SB CMP(1, 1) ISSUE(1, 13)
    WV(4) PF(1, 5) SB CMP(0, 0) ISSUE(0, 14)
    WV(4) PF(0, 6) SB CMP(1, 1) ISSUE(1, 15)
    WV(4) PF(1, 7) SB CMP(0, 0) ISSUE(0, 16)
    WV(4) PF(0, 0) SB CMP(1, 1) ISSUE(1, 17)
    EPI(1)
    WV(4) PF(1, 1) SB CMP(0, 0) ISSUE(0, 18)
    WV(4) PF(0, 2) SB CMP(1, 1) ISSUE(1, 19)
    WV(4) PF(1, 3) SB CMP(0, 0) ISSUE(0, 20)
    WV(4) PF(0, 4) SB CMP(1, 1) ISSUE(1, 21)
    WV(4) PF(1, 5) SB CMP(0, 0) ISSUE(0, 22)
    WV(4) PF(0, 6) SB CMP(1, 1) ISSUE(1, 23)
    WV(4) PF(1, 7) SB CMP(0, 0) ISSUE(0, 24)
    WV(4) PF(0, 0) SB CMP(1, 1) ISSUE(1, 25)
    EPI(2)
    WV(4) PF(1, 1) SB CMP(0, 0) ISSUE(0, 26)
    WV(4) PF(0, 2) SB CMP(1, 1) ISSUE(1, 27)
    WV(4) PF(1, 3) SB CMP(0, 0) ISSUE(0, 28)
    WV(4) PF(0, 4) SB CMP(1, 1) ISSUE(1, 29)
    WV(4) PF(1, 5) SB CMP(0, 0) ISSUE(0, 30)
    WV(4) PF(0, 6) SB CMP(1, 1) ISSUE(1, 31)
    WV(4) PF(1, 7) SB CMP(0, 0)
    WV(0)          SB CMP(1, 1)
    EPI(3)
}

// ---------------- select: 2-row pipeline, both rows' cold loads prefetched+pinned ------------
// Arithmetic/conversion/comparison orderings BIT-IDENTICAL to the passing version;
// only load timing moves (prefetch is value-preserving). asm pin prevents sinking (R11).
#define SELROW(row, zvv, pu) { \
    zs[t] = (zvv); \
    if (t == 0) lcnt = 0; \
    float nrm = (zvv) * (zvv); \
    _Pragma("unroll") \
    for (int m = 1; m < 64; m <<= 1) nrm += __shfl_xor(nrm, m, 64); \
    if (lane == 0) wred[w] = nrm; \
    float v[4]; \
    _Pragma("unroll") \
    for (int k = 0; k < 4; k++) v[k] = __half2float(((const __half*)&(pu))[k]); \
    float mn = fminf(fminf(v[0], v[1]), fminf(v[2], v[3])); \
    _Pragma("unroll") \
    for (int m = 1; m < 64; m <<= 1) mn = fminf(mn, __shfl_xor(mn, m, 64)); \
    if (lane == 0) wmin[w] = mn; \
    __syncthreads(); \
    const float zn = wred[0] + wred[1] + wred[2] + wred[3]; \
    const float g = fminf(fminf(wmin[0], wmin[1]), fminf(wmin[2], wmin[3])) + MARGIN; \
    _Pragma("unroll") \
    for (int k = 0; k < 4; k++) { \
        if (v[k] <= g) { \
            const int pos = atomicAdd(&lcnt, 1); \
            list[pos] = t * 4 + k; \
        } \
    } \
    __syncthreads(); \
    const int lane16 = t & 15, codei = t >> 4; \
    const int n = lcnt; \
    float bv = 3.0e38f; \
    int bi = 0x7fffffff; \
    for (int i = 0; i < n; i++) { \
        const int gg = list[i]; \
        const int cbase = ((gg >> 4) << 8) + (((gg >> 2) & 3) << 6) + ((gg & 3) << 2); \
        const int code = cbase + ((codei >> 2) << 4) + (codei & 3); \
        const float* zp = zs + lane16 * 16; \
        const float* ep = emb + (size_t)code * DIM + lane16 * 16; \
        float d = 0.f; \
        _Pragma("unroll") \
        for (int k = 0; k < 16; k += 4) { \
            const float4 ev = *(const float4*)(ep + k); \
            const float4 zv4 = *(const float4*)(zp + k); \
            d = fmaf(zv4.x, ev.x, d); \
            d = fmaf(zv4.y, ev.y, d); \
            d = fmaf(zv4.z, ev.z, d); \
            d = fmaf(zv4.w, ev.w, d); \
        } \
        _Pragma("unroll") \
        for (int m = 1; m <= 8; m <<= 1) d += __shfl_xor(d, m, 64); \
        if (lane16 == 0) { \
            const float tt = zn + enorm[code]; \
            const float s = tt - 2.0f * d; \
            if (s < bv || (s == bv && code < bi)) { bv = s; bi = code; } \
        } \
    } \
    if (lane16 == 0) { fs[codei] = bv; fi[codei] = bi; } \
    __syncthreads(); \
    if (t == 0) { \
        float b = fs[0]; int c = fi[0]; \
        _Pragma("unroll") \
        for (int k = 1; k < 16; k++) \
            if (fs[k] < b || (fs[k] == b && fi[k] < c)) { b = fs[k]; c = fi[k]; } \
        idxi[row] = c; \
        out_idx[row] = (float)c; \
    } \
    __syncthreads(); }

__global__ __launch_bounds__(256) void k_select(
        const float* __restrict__ zf, const float* __restrict__ emb,
        const float* __restrict__ enorm, const unsigned short* __restrict__ pvalh,
        int* __restrict__ idxi, float* __restrict__ out_idx) {
    const int t = threadIdx.x;
    const int lane = t & 63, w = t >> 6;
    __shared__ float zs[256];
    __shared__ float wred[4];
    __shared__ int lcnt;
    __shared__ int list[1024];
    __shared__ float fs[16];
    __shared__ int fi[16];
    __shared__ float wmin[4];

    const int r0 = blockIdx.x, r1 = blockIdx.x + 4096;
    // prefetch BOTH rows' cold inputs; pin so the compiler can't sink row1's loads
    const float zv0 = zf[(size_t)r0 * DIM + t];
    const float zv1 = zf[(size_t)r1 * DIM + t];
    const uint2 pu0 = *(const uint2*)(pvalh + (size_t)r0 * 1024 + t * 4);
    const uint2 pu1 = *(const uint2*)(pvalh + (size_t)r1 * 1024 + t * 4);
    asm volatile("" :: "v"(zv0), "v"(zv1), "v"(pu0.x), "v"(pu0.y), "v"(pu1.x), "v"(pu1.y));

    SELROW(r0, zv0, pu0)
    SELROW(r1, zv1, pu1)
}

// ---------------- gather z_q (NCHW) + fused loss: 4 c-tiles/block ----------------
__global__ __launch_bounds__(256) void k_gather(const float* __restrict__ emb,
                                                const float* __restrict__ zf,
                                                const int* __restrict__ idxi,
                                                float* __restrict__ zq,
                                                float* __restrict__ out_loss) {
    __shared__ float t[32][33];
    const int hw0 = blockIdx.x * 32;
    const int c0g = blockIdx.y * 128;
    const int b   = blockIdx.z;
    const int tx = threadIdx.x & 31, ty = threadIdx.x >> 5;
    float lsum = 0.f;
    int ids[4];
#pragma unroll
    for (int i = 0; i < 4; i++) ids[i] = idxi[b * 1024 + hw0 + ty + 8 * i];
#pragma unroll
    for (int j = 0; j < 4; j++) {
        const int c0 = c0g + j * 32;
#pragma unroll
        for (int i = 0; i < 4; i++) {
            const int hh = ty + 8 * i;
            const int n = b * 1024 + hw0 + hh;
            const float q = emb[(size_t)ids[i] * DIM + c0 + tx];
            const float zv = zf[(size_t)n * DIM + c0 + tx];
            const float d = q - zv;
            lsum += d * d;
            t[hh][tx] = q;
        }
        __syncthreads();
#pragma unroll
        for (int i = 0; i < 4; i++) {
            const int c = c0 + ty + 8 * i;
            zq[(size_t)(b * 256 + c) * 1024 + hw0 + tx] = t[tx][ty + 8 * i];
        }
        __syncthreads();
    }
#pragma unroll
    for (int m = 1; m < 64; m <<= 1) lsum += __shfl_xor(lsum, m, 64);
    __shared__ float wsum[4];
    const int lane = threadIdx.x & 63, w = threadIdx.x >> 6;
    if (lane == 0) wsum[w] = lsum;
    __syncthreads();
    if (threadIdx.x == 0) {
        const float total = wsum[0] + wsum[1] + wsum[2] + wsum[3];
        atomicAdd(out_loss, total * (1.25f / 2097152.0f));
    }
}

extern "C" void kernel_launch(void* const* d_in, const int* in_sizes, int n_in,
                              void* d_out, int out_size, void* d_ws, size_t ws_size,
                              hipStream_t stream) {
    const float* z   = (const float*)d_in[0];   // [8,256,32,32]
    const float* emb = (const float*)d_in[1];   // [16384,256]
    float* out = (float*)d_out;
    float* ws  = (float*)d_ws;

    float*          zf    = ws;                                   // 2,097,152 floats (8 MB)
    unsigned short* pvalh = (unsigned short*)(ws + 2097152);      // 8M halves (16 MB)
    unsigned short* zb    = (unsigned short*)(ws + 6291456);      // 2M halves (4 MB)
    unsigned short* eb    = (unsigned short*)(ws + 7340032);      // 4M halves (8 MB, tiled ebT)
    float*          enorm = ws + 9437184;                         // 16,384
    int*            idxi  = (int*)(ws + 9453568);                 // 8,192

    float* zq       = out;                   // [8,256,32,32] NCHW
    float* out_loss = out + 2097152;         // scalar
    float* out_idx  = out + 2097153;         // [8192] as float32

    k_prep<<<dim3(3073), 256, 0, stream>>>(z, emb, zf, zb, eb, enorm, out_loss);
    k_score<<<dim3(2048), 256, 0, stream>>>(zb, eb, enorm, pvalh);
    k_select<<<dim3(4096), 256, 0, stream>>>(zf, emb, enorm, pvalh, idxi, out_idx);
    k_gather<<<dim3(32, 2, 8), 256, 0, stream>>>(emb, zf, idxi, zq, out_loss);
}

// Round 18
// 196.650 us; speedup vs baseline: 1.0221x; 1.0221x over previous
//
#include <hip/hip_runtime.h>
#include <hip/hip_fp16.h>

#define DIM 256
#define MARGIN 2.25e-4f

typedef __bf16 bf8v __attribute__((ext_vector_type(8)));
typedef float f4v __attribute__((ext_vector_type(4)));

__device__ inline unsigned short f2bf(float x) {
    unsigned u = __float_as_uint(x);
    u += 0x7fffu + ((u >> 16) & 1u);   // RNE
    return (unsigned short)(u >> 16);
}

// ---------------- fused prep (2048 transpose + 1024 emb + 1 loss; grid 3073) ----------------
// eb is TILED (ebT): group g (16 codes) x K-step kk: 1024B tile [q(4)][m(16)][8 dims].
__global__ __launch_bounds__(256) void k_prep(const float* __restrict__ z,
                                              const float* __restrict__ emb,
                                              float* __restrict__ zf,
                                              unsigned short* __restrict__ zb,
                                              unsigned short* __restrict__ eb,
                                              float* __restrict__ enorm,
                                              float* __restrict__ out_loss) {
    const int bx = blockIdx.x;
    if (bx < 2048) {
        __shared__ float tt[32][33];
        const int hw0 = (bx & 31) * 32;
        const int d0  = ((bx >> 5) & 7) * 32;
        const int b   = bx >> 8;
        const int tx = threadIdx.x & 31, ty = threadIdx.x >> 5;
#pragma unroll
        for (int i = 0; i < 4; i++) {
            const int d = d0 + ty + 8 * i;
            tt[ty + 8 * i][tx] = z[(b * 256 + d) * 1024 + hw0 + tx];
        }
        __syncthreads();
#pragma unroll
        for (int i = 0; i < 4; i++) {
            const int hw = hw0 + ty + 8 * i;
            const float v = tt[tx][ty + 8 * i];
            const size_t o = (size_t)(b * 1024 + hw) * DIM + d0 + tx;
            zf[o] = v;
            zb[o] = f2bf(v);
        }
    } else if (bx < 3072) {
        const int s2 = bx - 2048;
        const int wave = threadIdx.x >> 6, lane = threadIdx.x & 63;
#pragma unroll
        for (int j = 0; j < 4; j++) {
            const int row = s2 * 16 + j * 4 + wave;
            const float4 v = *(const float4*)(emb + (size_t)row * DIM + lane * 4);
            ushort4 o;
            o.x = f2bf(v.x); o.y = f2bf(v.y); o.z = f2bf(v.z); o.w = f2bf(v.w);
            const int g = row >> 4, m = row & 15;
            const int kk = lane >> 3, qq = (lane >> 1) & 3, e = (lane & 1) * 4;
            *(ushort4*)(eb + (size_t)(g * 8 + kk) * 512 + qq * 128 + m * 8 + e) = o;
            float ss = v.x * v.x + v.y * v.y + v.z * v.z + v.w * v.w;
#pragma unroll
            for (int m2 = 1; m2 < 64; m2 <<= 1) ss += __shfl_xor(ss, m2, 64);
            if (lane == 0) enorm[row] = ss;
        }
    } else {
        if (threadIdx.x == 0) out_loss[0] = 0.f;
    }
}

// ---------------- bf16 MFMA scoring (R20: depth-2 B + Af dbuf at (256,3), measured best) -----
#define GLOADB(dst, voff, base) \
    asm volatile("global_load_dwordx4 %0, %1, %2" : "=&v"(dst) : "v"(voff), "s"(base))
#define SO(KK) ((unsigned)((((KK) >> 3) * 131072) + (((KK) & 7) * 1024)))

#define ISSUE(sl, KK) \
    GLOADB(Bp##sl##_0, voffb0 + SO(KK), eb); \
    GLOADB(Bp##sl##_1, voffb1 + SO(KK), eb); \
    GLOADB(Bp##sl##_2, voffb2 + SO(KK), eb); \
    GLOADB(Bp##sl##_3, voffb3 + SO(KK), eb);

#define MFMA4(rt, AF, sl) \
    acc[rt][0] = __builtin_amdgcn_mfma_f32_16x16x32_bf16(AF, Bp##sl##_0, acc[rt][0], 0, 0, 0); \
    acc[rt][1] = __builtin_amdgcn_mfma_f32_16x16x32_bf16(AF, Bp##sl##_1, acc[rt][1], 0, 0, 0); \
    acc[rt][2] = __builtin_amdgcn_mfma_f32_16x16x32_bf16(AF, Bp##sl##_2, acc[rt][2], 0, 0, 0); \
    acc[rt][3] = __builtin_amdgcn_mfma_f32_16x16x32_bf16(AF, Bp##sl##_3, acc[rt][3], 0, 0, 0);

#define PF(dp, kk) { \
    const int slot_ = (((kk) * 4 + q) ^ m15) * 8; \
    Af##dp##_0 = *(const bf8v*)&As[(m15)      * 256 + slot_]; \
    Af##dp##_1 = *(const bf8v*)&As[(16 + m15) * 256 + slot_]; \
    Af##dp##_2 = *(const bf8v*)&As[(32 + m15) * 256 + slot_]; \
    Af##dp##_3 = *(const bf8v*)&As[(48 + m15) * 256 + slot_]; }

#define CMP(P, sl) \
    __builtin_amdgcn_s_setprio(1); \
    MFMA4(0, Af##P##_0, sl) \
    MFMA4(1, Af##P##_1, sl) \
    MFMA4(2, Af##P##_2, sl) \
    MFMA4(3, Af##P##_3, sl) \
    __builtin_amdgcn_s_setprio(0);

#define WV(n) { asm volatile("s_waitcnt vmcnt(" #n ")" ::: "memory"); \
                __builtin_amdgcn_sched_barrier(0); }
#define SB __builtin_amdgcn_sched_barrier(0);

#define EPI(pp) { \
    const int by_ = nb * 4 + (pp); \
    const int gsl_ = wc * 4 + (m15 >> 2); \
    const float e0_ = en_lds[(pp) * 256 + wc * 64 +  0 + m15]; \
    const float e1_ = en_lds[(pp) * 256 + wc * 64 + 16 + m15]; \
    const float e2_ = en_lds[(pp) * 256 + wc * 64 + 32 + m15]; \
    const float e3_ = en_lds[(pp) * 256 + wc * 64 + 48 + m15]; \
    _Pragma("unroll") \
    for (int rt = 0; rt < 4; rt++) { \
        float sv[4]; \
        _Pragma("unroll") \
        for (int j = 0; j < 4; j++) { \
            float s_ = fmaf(-2.f, acc[rt][0][j], e0_); \
            s_ = fminf(s_, fmaf(-2.f, acc[rt][1][j], e1_)); \
            s_ = fminf(s_, fmaf(-2.f, acc[rt][2][j], e2_)); \
            s_ = fminf(s_, fmaf(-2.f, acc[rt][3][j], e3_)); \
            sv[j] = s_; \
        } \
        _Pragma("unroll") \
        for (int m = 1; m <= 2; m <<= 1) { \
            _Pragma("unroll") \
            for (int j = 0; j < 4; j++) sv[j] = fminf(sv[j], __shfl_xor(sv[j], m, 64)); \
        } \
        if ((m15 & 3) == 0) { \
            const int rl_ = rt * 16 + q * 4; \
            _Pragma("unroll") \
            for (int j = 0; j < 4; j++) \
                sm[(rl_ + j) * 16 + gsl_] = __half_as_ushort(__float2half_rn(sv[j])); \
        } \
    } \
    asm volatile("s_waitcnt lgkmcnt(0)" ::: "memory"); \
    __builtin_amdgcn_sched_barrier(0); \
    __builtin_amdgcn_s_barrier(); \
    __builtin_amdgcn_sched_barrier(0); \
    if (t < 128) { \
        const uint4 v_ = *(const uint4*)&sm[t * 8]; \
        *(uint4*)&pvalh[(size_t)(row0 + (t >> 1)) * 1024 + by_ * 16 + (t & 1) * 8] = v_; \
    } \
    __builtin_amdgcn_sched_barrier(0); \
    __builtin_amdgcn_s_barrier(); \
    __builtin_amdgcn_sched_barrier(0); \
    _Pragma("unroll") \
    for (int rt = 0; rt < 4; rt++) { \
        _Pragma("unroll") \
        for (int ct = 0; ct < 4; ct++) acc[rt][ct] = (f4v){0.f, 0.f, 0.f, 0.f}; \
    } }

__global__ __launch_bounds__(256, 3) void k_score(
        const unsigned short* __restrict__ zb, const unsigned short* __restrict__ eb,
        const float* __restrict__ enorm, unsigned short* __restrict__ pvalh) {
    __shared__ unsigned short As[64 * 256];   // 32 KB, swizzled: slot = chunk ^ (r&15)
    __shared__ unsigned short sm[64 * 16];    // 2 KB
    __shared__ float en_lds[1024];            // 4 KB
    const int bid = blockIdx.x;
    const int rx = (bid >> 3) & 127;
    const int nb = ((bid >> 10) << 3) + (bid & 7);
    const int row0 = rx * 64;
    const int t = threadIdx.x;
    const int lane = t & 63, wc = t >> 6;
    const int q = lane >> 4, m15 = lane & 15;

#pragma unroll
    for (int j = 0; j < 8; j++) {
        const int id = j * 256 + t;
        const int r = id >> 5, sl = id & 31;
        const int c = sl ^ (r & 15);
        __builtin_amdgcn_global_load_lds(
            (const __attribute__((address_space(1))) void*)(zb + (size_t)(row0 + r) * DIM + c * 8),
            (__attribute__((address_space(3))) void*)((char*)As + id * 16), 16, 0, 0);
    }
#pragma unroll
    for (int j = 0; j < 4; j++) {
        __builtin_amdgcn_global_load_lds(
            (const __attribute__((address_space(1))) void*)(enorm + nb * 1024 + j * 256 + t),
            (__attribute__((address_space(3))) void*)((char*)en_lds + (j * 256 + t) * 4), 4, 0, 0);
    }
    __syncthreads();

    f4v acc[4][4];
#pragma unroll
    for (int rt = 0; rt < 4; rt++)
#pragma unroll
        for (int ct = 0; ct < 4; ct++) acc[rt][ct] = (f4v){0.f, 0.f, 0.f, 0.f};

    const unsigned voffb0 = (unsigned)((nb * 64 + wc * 4 + 0) * 8192 + lane * 16);
    const unsigned voffb1 = (unsigned)((nb * 64 + wc * 4 + 1) * 8192 + lane * 16);
    const unsigned voffb2 = (unsigned)((nb * 64 + wc * 4 + 2) * 8192 + lane * 16);
    const unsigned voffb3 = (unsigned)((nb * 64 + wc * 4 + 3) * 8192 + lane * 16);

    bf8v Bp0_0, Bp0_1, Bp0_2, Bp0_3;
    bf8v Bp1_0, Bp1_1, Bp1_2, Bp1_3;
    bf8v Af0_0, Af0_1, Af0_2, Af0_3;
    bf8v Af1_0, Af1_1, Af1_2, Af1_3;

    ISSUE(0, 0) ISSUE(1, 1)
    PF(0, 0)

    WV(4) PF(1, 1) SB CMP(0, 0) ISSUE(0, 2)
    WV(4) PF(0, 2) SB CMP(1, 1) ISSUE(1, 3)
    WV(4) PF(1, 3) SB CMP(0, 0) ISSUE(0, 4)
    WV(4) PF(0, 4) SB CMP(1, 1) ISSUE(1, 5)
    WV(4) PF(1, 5) SB CMP(0, 0) ISSUE(0, 6)
    WV(4) PF(0, 6) SB CMP(1, 1) ISSUE(1, 7)
    WV(4) PF(1, 7) SB CMP(0, 0) ISSUE(0, 8)
    WV(4) PF(0, 0) SB CMP(1, 1) ISSUE(1, 9)
    EPI(0)
    WV(4) PF(1, 1) SB CMP(0, 0) ISSUE(0, 10)
    WV(4) PF(0, 2) SB CMP(1, 1) ISSUE(1, 11)
    WV(4) PF(1, 3) SB CMP(0, 0) ISSUE(0, 12)
    WV(4) PF(0, 4) SB CMP(1, 1) ISSUE(1, 13)
    WV(4) PF(1, 5) SB CMP(0, 0) ISSUE(0, 14)
    WV(4) PF(0, 6) SB CMP(1, 1) ISSUE(1, 15)
    WV(4) PF(1, 7) SB CMP(0, 0) ISSUE(0, 16)
    WV(4) PF(0, 0) SB CMP(1, 1) ISSUE(1, 17)
    EPI(1)
    WV(4) PF(1, 1) SB CMP(0, 0) ISSUE(0, 18)
    WV(4) PF(0, 2) SB CMP(1, 1) ISSUE(1, 19)
    WV(4) PF(1, 3) SB CMP(0, 0) ISSUE(0, 20)
    WV(4) PF(0, 4) SB CMP(1, 1) ISSUE(1, 21)
    WV(4) PF(1, 5) SB CMP(0, 0) ISSUE(0, 22)
    WV(4) PF(0, 6) SB CMP(1, 1) ISSUE(1, 23)
    WV(4) PF(1, 7) SB CMP(0, 0) ISSUE(0, 24)
    WV(4) PF(0, 0) SB CMP(1, 1) ISSUE(1, 25)
    EPI(2)
    WV(4) PF(1, 1) SB CMP(0, 0) ISSUE(0, 26)
    WV(4) PF(0, 2) SB CMP(1, 1) ISSUE(1, 27)
    WV(4) PF(1, 3) SB CMP(0, 0) ISSUE(0, 28)
    WV(4) PF(0, 4) SB CMP(1, 1) ISSUE(1, 29)
    WV(4) PF(1, 5) SB CMP(0, 0) ISSUE(0, 30)
    WV(4) PF(0, 6) SB CMP(1, 1) ISSUE(1, 31)
    WV(4) PF(1, 7) SB CMP(0, 0)
    WV(0)          SB CMP(1, 1)
    EPI(3)
}

// ---------------- select: grid-stride 2 rows/block; body bit-identical (frozen math) --------
__global__ __launch_bounds__(256) void k_select(
        const float* __restrict__ zf, const float* __restrict__ emb,
        const float* __restrict__ enorm, const unsigned short* __restrict__ pvalh,
        int* __restrict__ idxi, float* __restrict__ out_idx) {
    const int t = threadIdx.x;
    const int lane = t & 63, w = t >> 6;
    __shared__ float zs[256];
    __shared__ float wred[4];
    __shared__ int lcnt;
    __shared__ int list[1024];
    __shared__ float fs[16];
    __shared__ int fi[16];
    __shared__ float wmin[4];

    for (int row = blockIdx.x; row < 8192; row += 4096) {
        const float zv = zf[(size_t)row * DIM + t];
        zs[t] = zv;
        if (t == 0) lcnt = 0;
        float nrm = zv * zv;
#pragma unroll
        for (int m = 1; m < 64; m <<= 1) nrm += __shfl_xor(nrm, m, 64);
        if (lane == 0) wred[w] = nrm;

        const __half* p = (const __half*)(pvalh + (size_t)row * 1024 + t * 4);
        float v[4];
#pragma unroll
        for (int k = 0; k < 4; k++) v[k] = __half2float(p[k]);
        float mn = fminf(fminf(v[0], v[1]), fminf(v[2], v[3]));
#pragma unroll
        for (int m = 1; m < 64; m <<= 1) mn = fminf(mn, __shfl_xor(mn, m, 64));
        if (lane == 0) wmin[w] = mn;
        __syncthreads();
        const float zn = wred[0] + wred[1] + wred[2] + wred[3];
        const float g = fminf(fminf(wmin[0], wmin[1]), fminf(wmin[2], wmin[3])) + MARGIN;
#pragma unroll
        for (int k = 0; k < 4; k++) {
            if (v[k] <= g) {
                const int pos = atomicAdd(&lcnt, 1);
                list[pos] = t * 4 + k;
            }
        }
        __syncthreads();

        const int lane16 = t & 15, codei = t >> 4;
        const int n = lcnt;
        float bv = 3.0e38f;
        int bi = 0x7fffffff;
        for (int i = 0; i < n; i++) {
            const int gg = list[i];
            const int cbase = ((gg >> 4) << 8) + (((gg >> 2) & 3) << 6) + ((gg & 3) << 2);
            const int code = cbase + ((codei >> 2) << 4) + (codei & 3);
            const float* zp = zs + lane16 * 16;
            const float* ep = emb + (size_t)code * DIM + lane16 * 16;
            float d = 0.f;
#pragma unroll
            for (int k = 0; k < 16; k += 4) {
                const float4 ev = *(const float4*)(ep + k);
                const float4 zv4 = *(const float4*)(zp + k);
                d = fmaf(zv4.x, ev.x, d);
                d = fmaf(zv4.y, ev.y, d);
                d = fmaf(zv4.z, ev.z, d);
                d = fmaf(zv4.w, ev.w, d);
            }
#pragma unroll
            for (int m = 1; m <= 8; m <<= 1) d += __shfl_xor(d, m, 64);
            if (lane16 == 0) {
                const float tt = zn + enorm[code];
                const float s = tt - 2.0f * d;
                if (s < bv || (s == bv && code < bi)) { bv = s; bi = code; }
            }
        }
        if (lane16 == 0) { fs[codei] = bv; fi[codei] = bi; }
        __syncthreads();
        if (t == 0) {
            float b = fs[0]; int c = fi[0];
#pragma unroll
            for (int k = 1; k < 16; k++)
                if (fs[k] < b || (fs[k] == b && fi[k] < c)) { b = fs[k]; c = fi[k]; }
            idxi[row] = c;
            out_idx[row] = (float)c;
        }
        __syncthreads();
    }
}

// ---------------- gather z_q (NCHW) + fused loss: 4 c-tiles/block ----------------
__global__ __launch_bounds__(256) void k_gather(const float* __restrict__ emb,
                                                const float* __restrict__ zf,
                                                const int* __restrict__ idxi,
                                                float* __restrict__ zq,
                                                float* __restrict__ out_loss) {
    __shared__ float t[32][33];
    const int hw0 = blockIdx.x * 32;
    const int c0g = blockIdx.y * 128;
    const int b   = blockIdx.z;
    const int tx = threadIdx.x & 31, ty = threadIdx.x >> 5;
    float lsum = 0.f;
    int ids[4];
#pragma unroll
    for (int i = 0; i < 4; i++) ids[i] = idxi[b * 1024 + hw0 + ty + 8 * i];
#pragma unroll
    for (int j = 0; j < 4; j++) {
        const int c0 = c0g + j * 32;
#pragma unroll
        for (int i = 0; i < 4; i++) {
            const int hh = ty + 8 * i;
            const int n = b * 1024 + hw0 + hh;
            const float q = emb[(size_t)ids[i] * DIM + c0 + tx];
            const float zv = zf[(size_t)n * DIM + c0 + tx];
            const float d = q - zv;
            lsum += d * d;
            t[hh][tx] = q;
        }
        __syncthreads();
#pragma unroll
        for (int i = 0; i < 4; i++) {
            const int c = c0 + ty + 8 * i;
            zq[(size_t)(b * 256 + c) * 1024 + hw0 + tx] = t[tx][ty + 8 * i];
        }
        __syncthreads();
    }
#pragma unroll
    for (int m = 1; m < 64; m <<= 1) lsum += __shfl_xor(lsum, m, 64);
    __shared__ float wsum[4];
    const int lane = threadIdx.x & 63, w = threadIdx.x >> 6;
    if (lane == 0) wsum[w] = lsum;
    __syncthreads();
    if (threadIdx.x == 0) {
        const float total = wsum[0] + wsum[1] + wsum[2] + wsum[3];
        atomicAdd(out_loss, total * (1.25f / 2097152.0f));
    }
}

extern "C" void kernel_launch(void* const* d_in, const int* in_sizes, int n_in,
                              void* d_out, int out_size, void* d_ws, size_t ws_size,
                              hipStream_t stream) {
    const float* z   = (const float*)d_in[0];   // [8,256,32,32]
    const float* emb = (const float*)d_in[1];   // [16384,256]
    float* out = (float*)d_out;
    float* ws  = (float*)d_ws;

    float*          zf    = ws;                                   // 2,097,152 floats (8 MB)
    unsigned short* pvalh = (unsigned short*)(ws + 2097152);      // 8M halves (16 MB)
    unsigned short* zb    = (unsigned short*)(ws + 6291456);      // 2M halves (4 MB)
    unsigned short* eb    = (unsigned short*)(ws + 7340032);      // 4M halves (8 MB, tiled ebT)
    float*          enorm = ws + 9437184;                         // 16,384
    int*            idxi  = (int*)(ws + 9453568);                 // 8,192

    float* zq       = out;                   // [8,256,32,32] NCHW
    float* out_loss = out + 2097152;         // scalar
    float* out_idx  = out + 2097153;         // [8192] as float32

    k_prep<<<dim3(3073), 256, 0, stream>>>(z, emb, zf, zb, eb, enorm, out_loss);
    k_score<<<dim3(2048), 256, 0, stream>>>(zb, eb, enorm, pvalh);
    k_select<<<dim3(4096), 256, 0, stream>>>(zf, emb, enorm, pvalh, idxi, out_idx);
    k_gather<<<dim3(32, 2, 8), 256, 0, stream>>>(emb, zf, idxi, zq, out_loss);
}